// Round 6
// baseline (33.692 us; speedup 1.0000x reference)
//
#include <hip/hip_runtime.h>
#include <hip/hip_bf16.h>

// ---- problem constants ----
#define B_TOK   128
#define E_TOP   4
#define NEXP    32
#define KDIM    512
#define CDIM    1024
#define PAIRS   (B_TOK * E_TOP)   // 512
#define HALF_C  (CDIM / 2)        // 512

#define ALPHA   1.702f
#define LIMIT   7.0f

#define TT      32                // tokens per item -> 1 item/expert (typ.)
#define MAXIT   48

typedef __attribute__((ext_vector_type(8))) short short8;   // bf16x8 frag
typedef __attribute__((ext_vector_type(4))) float f32x4;

// ws layout:
//   [0,      32768)  lists: u16[32][512]
//   [32768, +576)    itemE/itemB/itemN/nItems
//   [40960, +131072) xpk: bf16[128][512]  (k-major, frag-trivial)
#define WS_ITEMS  32768
#define WS_XPK    40960

__device__ __forceinline__ unsigned pk2(float a, float b) {
    union { __hip_bfloat16 h; unsigned short u; } ca, cb;
    ca.h = __float2bfloat16(a);
    cb.h = __float2bfloat16(b);
    return (unsigned)ca.u | ((unsigned)cb.u << 16);
}

__device__ __forceinline__ short8 cvt8(float4 lo, float4 hi) {
    union { unsigned u[4]; short8 s; } r;
    r.u[0] = pk2(lo.x, lo.y);
    r.u[1] = pk2(lo.z, lo.w);
    r.u[2] = pk2(hi.x, hi.y);
    r.u[3] = pk2(hi.z, hi.w);
    return r.s;
}

__device__ __forceinline__ float glu_act(float g, float l) {
    g = fminf(g, LIMIT);
    l = fminf(fmaxf(l, -LIMIT), LIMIT);
    const float sg = 1.0f / (1.0f + __expf(-ALPHA * g));
    return (g * sg) * (l + 1.0f);
}

#define LDF4(p, off) (*(const float4*)((p) + (off)))

// =====================================================================
// Kernel 0: pack x [128,512] fp32 -> bf16 k-major (128 KB, L2-resident).
// 32 blocks x 256 threads, 8 floats each.
// =====================================================================
__global__ void pack_x_kernel(const float* __restrict__ x,
                              uint4* __restrict__ xpk) {
    const int i = blockIdx.x * 256 + threadIdx.x;   // 8192 quads
    const float4 a = LDF4(x, i * 8);
    const float4 b = LDF4(x, i * 8 + 4);
    uint4 r;
    r.x = pk2(a.x, a.y); r.y = pk2(a.z, a.w);
    r.z = pk2(b.x, b.y); r.w = pk2(b.z, b.w);
    xpk[i] = r;
}

// =====================================================================
// Kernel 1: bucket (b,e) pairs by expert, build TT=32 work items.
// =====================================================================
__global__ void bucket_kernel(const int* __restrict__ idx,
                              unsigned short* __restrict__ lists,
                              int* __restrict__ itemE,
                              int* __restrict__ itemB,
                              int* __restrict__ itemN,
                              int* __restrict__ nItems) {
    __shared__ int cnt[NEXP];
    const int t = threadIdx.x;            // 0..511
    if (t < NEXP) cnt[t] = 0;
    __syncthreads();
    const int e = idx[t];
    const int pos = atomicAdd(&cnt[e], 1);
    lists[e * PAIRS + pos] = (unsigned short)t;
    __syncthreads();
    if (t == 0) {
        int n = 0;
        for (int ee = 0; ee < NEXP; ++ee) {
            const int c = cnt[ee];
            for (int b = 0; b < c; b += TT) {
                itemE[n] = ee;
                itemB[n] = b;
                itemN[n] = min(TT, c - b);
                ++n;
            }
        }
        *nItems = n;
    }
}

// =====================================================================
// Kernel 2: block = (32-ch chunk, expert item). 4 waves = 2 k-halves x
// 2 ch-groups; wave: 16 channels x K/2, 8 MFMA steps x 2 MFMAs (tok
// 0-15 / 16-31) sharing the A(W) fragment.
//  - W: global fp32 -> VGPR ring depth 4, cvt to bf16 per step
//  - x: DIRECT global bf16 frag loads from xpk (L2-hot), ring depth 2
//  - no LDS except the 4 KB 2-way k-combine; barrier only at combine
// =====================================================================
__global__ __launch_bounds__(256, 4) void moe_mlp1_kernel(
    const float* __restrict__ w,      // [32, 1024, 512]
    const float* __restrict__ bias,   // [32, 1024]
    const char* __restrict__ xpk,     // bf16 [128][512]
    const unsigned short* __restrict__ lists,
    const int* __restrict__ itemE,
    const int* __restrict__ itemB,
    const int* __restrict__ itemN,
    const int* __restrict__ nItems,
    float* __restrict__ out)          // [512, 512] fp32
{
    __shared__ float red[2][64][8];   // 4 KB

    const int it = blockIdx.y;
    if (it >= *nItems) return;
    const int e     = itemE[it];
    const int tBase = itemB[it];
    const int nT    = itemN[it];
    const int cBase = blockIdx.x * 32;

    const int tid  = threadIdx.x;
    const int wv   = tid >> 6;
    const int lane = tid & 63;
    const int kh   = wv >> 1;          // k-half
    const int cs   = wv & 1;           // channel sub-group
    const int kg   = lane >> 4;        // k-group within MFMA step
    const int c16  = lane & 15;

    const float* wp = w + ((size_t)e * CDIM + cBase + cs * 16 + c16) * KDIM
                        + kh * 256 + kg * 8;

    // B-frag base addresses (per-lane constant rows)
    const int tA  = lane & 15;
    const int pr0 = (tA < nT)      ? (int)lists[e * PAIRS + tBase + tA]      : 0;
    const int pr1 = (tA + 16 < nT) ? (int)lists[e * PAIRS + tBase + tA + 16] : 0;
    const char* xb0 = xpk + (pr0 >> 2) * 1024 + kh * 512 + kg * 16;
    const char* xb1 = xpk + (pr1 >> 2) * 1024 + kh * 512 + kg * 16;

    // hoisted bias (tiny, overlaps with K-loop)
    const float4 bv = *(const float4*)(bias + (size_t)e * CDIM + cBase
                                       + cs * 16 + kg * 4);

    // ---- prefetch rings: W depth 4, x depth 2 ----
    float4 w0[4], w1[4];
    short8 xv0[2], xv1[2];
    #pragma unroll
    for (int p = 0; p < 4; ++p) {
        w0[p] = LDF4(wp, p * 32);
        w1[p] = LDF4(wp, p * 32 + 4);
    }
    #pragma unroll
    for (int p = 0; p < 2; ++p) {
        xv0[p] = *(const short8*)(xb0 + p * 64);
        xv1[p] = *(const short8*)(xb1 + p * 64);
    }

    f32x4 acc0 = {0.f, 0.f, 0.f, 0.f};
    f32x4 acc1 = {0.f, 0.f, 0.f, 0.f};

    #pragma unroll
    for (int s = 0; s < 8; ++s) {
        const short8 a = cvt8(w0[s & 3], w1[s & 3]);
        if (s + 4 < 8) {
            w0[s & 3] = LDF4(wp, (s + 4) * 32);
            w1[s & 3] = LDF4(wp, (s + 4) * 32 + 4);
        }
        const short8 b0 = xv0[s & 1];
        const short8 b1 = xv1[s & 1];
        if (s + 2 < 8) {
            xv0[s & 1] = *(const short8*)(xb0 + (s + 2) * 64);
            xv1[s & 1] = *(const short8*)(xb1 + (s + 2) * 64);
        }
        acc0 = __builtin_amdgcn_mfma_f32_16x16x32_bf16(a, b0, acc0, 0, 0, 0);
        acc1 = __builtin_amdgcn_mfma_f32_16x16x32_bf16(a, b1, acc1, 0, 0, 0);
    }

    // ---- 2-way k-combine + lane-local GLU epilogue ----
    if (kh == 1) {
        #pragma unroll
        for (int i = 0; i < 4; ++i) {
            red[cs][lane][i]     = acc0[i];
            red[cs][lane][4 + i] = acc1[i];
        }
    }
    __syncthreads();
    if (kh == 0) {
        #pragma unroll
        for (int i = 0; i < 4; ++i) {
            acc0[i] += red[cs][lane][i];
            acc1[i] += red[cs][lane][4 + i];
        }
        const int cb = cBase + cs * 16 + kg * 4;   // channels cb..cb+3, %4==0
        if (tA < nT) {
            float2 o;
            o.x = glu_act(acc0[0] + bv.x, acc0[1] + bv.y);
            o.y = glu_act(acc0[2] + bv.z, acc0[3] + bv.w);
            *(float2*)&out[(size_t)pr0 * HALF_C + (cb >> 1)] = o;
        }
        if (tA + 16 < nT) {
            float2 o;
            o.x = glu_act(acc1[0] + bv.x, acc1[1] + bv.y);
            o.y = glu_act(acc1[2] + bv.z, acc1[3] + bv.w);
            *(float2*)&out[(size_t)pr1 * HALF_C + (cb >> 1)] = o;
        }
    }
}

extern "C" void kernel_launch(void* const* d_in, const int* in_sizes, int n_in,
                              void* d_out, int out_size, void* d_ws, size_t ws_size,
                              hipStream_t stream) {
    const float* x    = (const float*)d_in[0];
    const int*   idx  = (const int*)d_in[1];
    const float* w    = (const float*)d_in[2];
    const float* bias = (const float*)d_in[3];
    float* out = (float*)d_out;

    char* wsb = (char*)d_ws;
    unsigned short* lists = (unsigned short*)wsb;
    int* itemE  = (int*)(wsb + WS_ITEMS);
    int* itemB  = (int*)(wsb + WS_ITEMS + MAXIT * 4);
    int* itemN  = (int*)(wsb + WS_ITEMS + MAXIT * 8);
    int* nItems = (int*)(wsb + WS_ITEMS + MAXIT * 12);
    char* xpk   = wsb + WS_XPK;

    pack_x_kernel<<<32, 256, 0, stream>>>(x, (uint4*)xpk);
    bucket_kernel<<<1, PAIRS, 0, stream>>>(idx, lists, itemE, itemB, itemN, nItems);

    dim3 grid(CDIM / 32, MAXIT);   // (32, 48); ~1024 working blocks = 4/CU
    moe_mlp1_kernel<<<grid, 256, 0, stream>>>(w, bias, xpk, lists,
                                              itemE, itemB, itemN, nItems, out);
}

// Round 7
// 25.339 us; speedup vs baseline: 1.3296x; 1.3296x over previous
//
#include <hip/hip_runtime.h>
#include <hip/hip_bf16.h>

// ---- problem constants ----
#define B_TOK   128
#define E_TOP   4
#define NEXP    32
#define KDIM    512
#define CDIM    1024
#define PAIRS   (B_TOK * E_TOP)   // 512
#define HALF_C  (CDIM / 2)        // 512

#define ALPHA   1.702f
#define LIMIT   7.0f

#define TT      32                // tokens per item -> 1 item/expert (typ.)
#define MAXIT   48

typedef __attribute__((ext_vector_type(8))) short short8;   // bf16x8 frag
typedef __attribute__((ext_vector_type(4))) float f32x4;

// ws layout:
//   [0,      32768)  lists: u16[32][512]
//   [32768, +576)    itemE/itemB/itemN/nItems
//   [40960, +131072) xpk: bf16[128][512]  (k-major, frag-trivial, L2-hot)
#define WS_ITEMS  32768
#define WS_XPK    40960

__device__ __forceinline__ unsigned pk2(float a, float b) {
    union { __hip_bfloat16 h; unsigned short u; } ca, cb;
    ca.h = __float2bfloat16(a);
    cb.h = __float2bfloat16(b);
    return (unsigned)ca.u | ((unsigned)cb.u << 16);
}

__device__ __forceinline__ short8 cvt8(float4 lo, float4 hi) {
    union { unsigned u[4]; short8 s; } r;
    r.u[0] = pk2(lo.x, lo.y);
    r.u[1] = pk2(lo.z, lo.w);
    r.u[2] = pk2(hi.x, hi.y);
    r.u[3] = pk2(hi.z, hi.w);
    return r.s;
}

__device__ __forceinline__ float glu_act(float g, float l) {
    g = fminf(g, LIMIT);
    l = fminf(fmaxf(l, -LIMIT), LIMIT);
    const float sg = 1.0f / (1.0f + __expf(-ALPHA * g));
    return (g * sg) * (l + 1.0f);
}

#define LDF4(p, off) (*(const float4*)((p) + (off)))

// =====================================================================
// Kernel 1 (prep): block 0 buckets (b,e) pairs by expert and builds the
// TT=32 work items; blocks 1..32 pack x fp32 -> bf16 k-major (128 KB).
// Output values order-independent -> deterministic.
// =====================================================================
__global__ void prep_kernel(const float* __restrict__ x,
                            uint4* __restrict__ xpk,
                            const int* __restrict__ idx,
                            unsigned short* __restrict__ lists,
                            int* __restrict__ itemE,
                            int* __restrict__ itemB,
                            int* __restrict__ itemN,
                            int* __restrict__ nItems) {
    if (blockIdx.x != 0) {
        const int i = (blockIdx.x - 1) * 256 + threadIdx.x;   // 8192 octets
        const float4 a = LDF4(x, i * 8);
        const float4 b = LDF4(x, i * 8 + 4);
        uint4 r;
        r.x = pk2(a.x, a.y); r.y = pk2(a.z, a.w);
        r.z = pk2(b.x, b.y); r.w = pk2(b.z, b.w);
        xpk[i] = r;
        return;
    }
    __shared__ int cnt[NEXP];
    const int t = threadIdx.x;            // 0..255
    if (t < NEXP) cnt[t] = 0;
    __syncthreads();
    #pragma unroll
    for (int r = 0; r < 2; ++r) {
        const int p = t + r * 256;
        const int e = idx[p];
        const int pos = atomicAdd(&cnt[e], 1);
        lists[e * PAIRS + pos] = (unsigned short)p;
    }
    __syncthreads();
    if (t == 0) {
        int n = 0;
        for (int ee = 0; ee < NEXP; ++ee) {
            const int c = cnt[ee];
            for (int b = 0; b < c; b += TT) {
                itemE[n] = ee;
                itemB[n] = b;
                itemN[n] = min(TT, c - b);
                ++n;
            }
        }
        *nItems = n;
    }
}

// =====================================================================
// Kernel 2: block = (32-ch chunk, expert item). 4 waves = 2 k-halves x
// 2 ch-groups; wave: 16 channels x K/2, 8 MFMA steps x 2 MFMAs (tok
// 0-15 / 16-31) sharing the A(W) fragment.
//  - W: global fp32 -> VGPR ring depth 4 (issued first), cvt bf16/step
//  - x: bf16 frags staged LDS-direct via global_load_lds (1 call/frag,
//       per-lane source from xpk, wave-uniform dest) -- no VGPR trip,
//       no cvt, conflict-free ds_read_b128 in the K-loop.
//  - 4 KB LDS 2-way k-combine; lane-local GLU epilogue.
// W is streamed from HBM exactly once (64 MB total).
// =====================================================================
__global__ __launch_bounds__(256, 4) void moe_mlp1_kernel(
    const float* __restrict__ w,      // [32, 1024, 512]
    const float* __restrict__ bias,   // [32, 1024]
    const char* __restrict__ xpk,     // bf16 [128][512]
    const unsigned short* __restrict__ lists,
    const int* __restrict__ itemE,
    const int* __restrict__ itemB,
    const int* __restrict__ itemN,
    const int* __restrict__ nItems,
    float* __restrict__ out)          // [512, 512] fp32
{
    __shared__ char  xbl[32 * 1024];   // 32 frags x 1 KB
    __shared__ float red[2][64][8];    // 4 KB

    const int it = blockIdx.y;
    if (it >= *nItems) return;
    const int e     = itemE[it];
    const int tBase = itemB[it];
    const int nT    = itemN[it];
    const int cBase = blockIdx.x * 32;

    const int tid  = threadIdx.x;
    const int wv   = tid >> 6;
    const int lane = tid & 63;
    const int kh   = wv >> 1;          // k-half
    const int cs   = wv & 1;           // channel sub-group
    const int kg   = lane >> 4;        // k-group within MFMA step
    const int c16  = lane & 15;
    const int tA   = lane & 15;

    // ---- W ring (depth 4) issued FIRST: longest-latency stream ----
    const float* wp = w + ((size_t)e * CDIM + cBase + cs * 16 + c16) * KDIM
                        + kh * 256 + kg * 8;
    float4 w0[4], w1[4];
    #pragma unroll
    for (int p = 0; p < 4; ++p) {
        w0[p] = LDF4(wp, p * 32);
        w1[p] = LDF4(wp, p * 32 + 4);
    }

    // ---- token rows (for x staging + output) ----
    const int pr0 = (tA < nT)      ? (int)lists[e * PAIRS + tBase + tA]      : -1;
    const int pr1 = (tA + 16 < nT) ? (int)lists[e * PAIRS + tBase + tA + 16] : -1;
    const int rr0 = (pr0 >= 0) ? (pr0 >> 2) : ((int)lists[e * PAIRS + tBase] >> 2);
    const int rr1 = (pr1 >= 0) ? (pr1 >> 2) : ((int)lists[e * PAIRS + tBase] >> 2);

    // ---- stage x: 8 global_load_lds per wave, one 1 KB frag each ----
    // frag f = s*2 + half; lane l = t16 + 16*kg holds token t16's bytes
    // [s*64 + kg*16, +16) of its packed row -> dest byte f*1024 + l*16.
    #pragma unroll
    for (int j = 0; j < 8; ++j) {
        const int f   = wv * 8 + j;
        const int s   = f >> 1;
        const int hlf = f & 1;
        const char* src = xpk + (size_t)(hlf ? rr1 : rr0) * 1024 + s * 64 + kg * 16;
        __builtin_amdgcn_global_load_lds(
            (const __attribute__((address_space(1))) void*)src,
            (__attribute__((address_space(3))) void*)&xbl[f * 1024],
            16, 0, 0);
    }

    // hoisted bias (overlaps with staging/loads)
    const float4 bv = *(const float4*)(bias + (size_t)e * CDIM + cBase
                                       + cs * 16 + kg * 4);

    __syncthreads();   // frags landed (compiler drains vmcnt/lgkm)

    // ---- barrier-free K-loop: 8 steps, 2 MFMAs/step ----
    f32x4 acc0 = {0.f, 0.f, 0.f, 0.f};
    f32x4 acc1 = {0.f, 0.f, 0.f, 0.f};
    const char* xb = &xbl[(kh * 8) * 2048 + lane * 16];
    #pragma unroll
    for (int s = 0; s < 8; ++s) {
        const short8 a = cvt8(w0[s & 3], w1[s & 3]);
        if (s + 4 < 8) {
            w0[s & 3] = LDF4(wp, (s + 4) * 32);
            w1[s & 3] = LDF4(wp, (s + 4) * 32 + 4);
        }
        const short8 b0 = *(const short8*)(xb + s * 2048);
        const short8 b1 = *(const short8*)(xb + s * 2048 + 1024);
        acc0 = __builtin_amdgcn_mfma_f32_16x16x32_bf16(a, b0, acc0, 0, 0, 0);
        acc1 = __builtin_amdgcn_mfma_f32_16x16x32_bf16(a, b1, acc1, 0, 0, 0);
    }

    // ---- 2-way k-combine + lane-local GLU epilogue ----
    if (kh == 1) {
        #pragma unroll
        for (int i = 0; i < 4; ++i) {
            red[cs][lane][i]     = acc0[i];
            red[cs][lane][4 + i] = acc1[i];
        }
    }
    __syncthreads();
    if (kh == 0) {
        #pragma unroll
        for (int i = 0; i < 4; ++i) {
            acc0[i] += red[cs][lane][i];
            acc1[i] += red[cs][lane][4 + i];
        }
        const int cb = cBase + cs * 16 + kg * 4;   // channels cb..cb+3
        if (pr0 >= 0) {
            float2 o;
            o.x = glu_act(acc0[0] + bv.x, acc0[1] + bv.y);
            o.y = glu_act(acc0[2] + bv.z, acc0[3] + bv.w);
            *(float2*)&out[(size_t)pr0 * HALF_C + (cb >> 1)] = o;
        }
        if (pr1 >= 0) {
            float2 o;
            o.x = glu_act(acc1[0] + bv.x, acc1[1] + bv.y);
            o.y = glu_act(acc1[2] + bv.z, acc1[3] + bv.w);
            *(float2*)&out[(size_t)pr1 * HALF_C + (cb >> 1)] = o;
        }
    }
}

extern "C" void kernel_launch(void* const* d_in, const int* in_sizes, int n_in,
                              void* d_out, int out_size, void* d_ws, size_t ws_size,
                              hipStream_t stream) {
    const float* x    = (const float*)d_in[0];
    const int*   idx  = (const int*)d_in[1];
    const float* w    = (const float*)d_in[2];
    const float* bias = (const float*)d_in[3];
    float* out = (float*)d_out;

    char* wsb = (char*)d_ws;
    unsigned short* lists = (unsigned short*)wsb;
    int* itemE  = (int*)(wsb + WS_ITEMS);
    int* itemB  = (int*)(wsb + WS_ITEMS + MAXIT * 4);
    int* itemN  = (int*)(wsb + WS_ITEMS + MAXIT * 8);
    int* nItems = (int*)(wsb + WS_ITEMS + MAXIT * 12);
    char* xpk   = wsb + WS_XPK;

    prep_kernel<<<33, 256, 0, stream>>>(x, (uint4*)xpk, idx, lists,
                                        itemE, itemB, itemN, nItems);

    dim3 grid(CDIM / 32, MAXIT);   // (32, 48); ~1024 working blocks = 4/CU
    moe_mlp1_kernel<<<grid, 256, 0, stream>>>(w, bias, xpk, lists,
                                              itemE, itemB, itemN, nItems, out);
}

// Round 8
// 25.124 us; speedup vs baseline: 1.3410x; 1.0085x over previous
//
#include <hip/hip_runtime.h>
#include <hip/hip_bf16.h>

// ---- problem constants ----
#define B_TOK   128
#define E_TOP   4
#define NEXP    32
#define KDIM    512
#define CDIM    1024
#define PAIRS   (B_TOK * E_TOP)   // 512
#define HALF_C  (CDIM / 2)        // 512

#define ALPHA   1.702f
#define LIMIT   7.0f

#define TT      32                // tokens per item -> 1 item/expert (typ.)
#define MAXIT   48                // hard bound: 16 + 32
#define ITSTRIDE 32               // grid.y

typedef __attribute__((ext_vector_type(8))) short short8;   // bf16x8 frag
typedef __attribute__((ext_vector_type(4))) float f32x4;

// ws layout:
//   [0,      32768)  lists: u16[32][512]
//   [32768, +576)    itemE/itemB/itemN/nItems
//   [40960, +131072) xpk: bf16[128][512]  (k-major, frag-trivial, L2-hot)
#define WS_ITEMS  32768
#define WS_XPK    40960

__device__ __forceinline__ unsigned pk2(float a, float b) {
    union { __hip_bfloat16 h; unsigned short u; } ca, cb;
    ca.h = __float2bfloat16(a);
    cb.h = __float2bfloat16(b);
    return (unsigned)ca.u | ((unsigned)cb.u << 16);
}

__device__ __forceinline__ short8 cvt8(float4 lo, float4 hi) {
    union { unsigned u[4]; short8 s; } r;
    r.u[0] = pk2(lo.x, lo.y);
    r.u[1] = pk2(lo.z, lo.w);
    r.u[2] = pk2(hi.x, hi.y);
    r.u[3] = pk2(hi.z, hi.w);
    return r.s;
}

__device__ __forceinline__ float glu_act(float g, float l) {
    g = fminf(g, LIMIT);
    l = fminf(fmaxf(l, -LIMIT), LIMIT);
    const float sg = 1.0f / (1.0f + __expf(-ALPHA * g));
    return (g * sg) * (l + 1.0f);
}

#define LDF4(p, off) (*(const float4*)((p) + (off)))

// =====================================================================
// Kernel 1 (prep): block 0 buckets (b,e) pairs by expert and builds the
// TT=32 work items; blocks 1..32 pack x fp32 -> bf16 k-major (128 KB).
// Output values order-independent -> deterministic.
// =====================================================================
__global__ void prep_kernel(const float* __restrict__ x,
                            uint4* __restrict__ xpk,
                            const int* __restrict__ idx,
                            unsigned short* __restrict__ lists,
                            int* __restrict__ itemE,
                            int* __restrict__ itemB,
                            int* __restrict__ itemN,
                            int* __restrict__ nItems) {
    if (blockIdx.x != 0) {
        const int i = (blockIdx.x - 1) * 256 + threadIdx.x;   // 8192 octets
        const float4 a = LDF4(x, i * 8);
        const float4 b = LDF4(x, i * 8 + 4);
        uint4 r;
        r.x = pk2(a.x, a.y); r.y = pk2(a.z, a.w);
        r.z = pk2(b.x, b.y); r.w = pk2(b.z, b.w);
        xpk[i] = r;
        return;
    }
    __shared__ int cnt[NEXP];
    const int t = threadIdx.x;            // 0..255
    if (t < NEXP) cnt[t] = 0;
    __syncthreads();
    #pragma unroll
    for (int r = 0; r < 2; ++r) {
        const int p = t + r * 256;
        const int e = idx[p];
        const int pos = atomicAdd(&cnt[e], 1);
        lists[e * PAIRS + pos] = (unsigned short)p;
    }
    __syncthreads();
    if (t == 0) {
        int n = 0;
        for (int ee = 0; ee < NEXP; ++ee) {
            const int c = cnt[ee];
            for (int b = 0; b < c; b += TT) {
                itemE[n] = ee;
                itemB[n] = b;
                itemN[n] = min(TT, c - b);
                ++n;
            }
        }
        *nItems = n;
    }
}

// =====================================================================
// Kernel 2: block = (32-ch chunk, expert item). 4 waves = 2 k-halves x
// 2 ch-groups; wave: 16 channels x K/2, 8 MFMA steps x 2 MFMAs (tok
// 0-15 / 16-31) sharing the A(W) fragment.
//  - x: bf16 frags staged LDS-direct via global_load_lds, then ONE
//       barrier (drains only these cheap L2-hot loads).
//  - W: ALL 16 dwordx4 issued right after the barrier into a depth-8
//       VGPR ring; compiler emits counted vmcnt(14-2s) down the
//       unrolled loop -> the wave's whole 16 KB W stream is in flight
//       while earlier steps compute. No barrier ever drains W.
//  - 4 KB LDS 2-way k-combine; lane-local GLU epilogue.
// =====================================================================
__global__ __launch_bounds__(256, 4) void moe_mlp1_kernel(
    const float* __restrict__ w,      // [32, 1024, 512]
    const float* __restrict__ bias,   // [32, 1024]
    const char* __restrict__ xpk,     // bf16 [128][512]
    const unsigned short* __restrict__ lists,
    const int* __restrict__ itemE,
    const int* __restrict__ itemB,
    const int* __restrict__ itemN,
    const int* __restrict__ nItems,
    float* __restrict__ out)          // [512, 512] fp32
{
    __shared__ char  xbl[32 * 1024];   // 32 frags x 1 KB
    __shared__ float red[2][64][8];    // 4 KB

    const int nI = *nItems;
    const int tid  = threadIdx.x;
    const int wv   = tid >> 6;
    const int lane = tid & 63;
    const int kh   = wv >> 1;          // k-half
    const int cs   = wv & 1;           // channel sub-group
    const int kg   = lane >> 4;        // k-group within MFMA step
    const int c16  = lane & 15;
    const int tA   = lane & 15;
    const int cBase = blockIdx.x * 32;

    for (int it = blockIdx.y; it < nI; it += ITSTRIDE) {
        if (it != (int)blockIdx.y) __syncthreads();   // xbl/red reuse

        const int e     = itemE[it];
        const int tBase = itemB[it];
        const int nT    = itemN[it];

        // ---- token rows ----
        const int pr0 = (tA < nT)      ? (int)lists[e * PAIRS + tBase + tA]      : -1;
        const int pr1 = (tA + 16 < nT) ? (int)lists[e * PAIRS + tBase + tA + 16] : -1;
        const int rfb = (int)lists[e * PAIRS + tBase] >> 2;
        const int rr0 = (pr0 >= 0) ? (pr0 >> 2) : rfb;
        const int rr1 = (pr1 >= 0) ? (pr1 >> 2) : rfb;

        // ---- stage x: 8 global_load_lds per wave, one 1 KB frag each ----
        #pragma unroll
        for (int j = 0; j < 8; ++j) {
            const int f   = wv * 8 + j;
            const int s   = f >> 1;
            const int hlf = f & 1;
            const char* src = xpk + (size_t)(hlf ? rr1 : rr0) * 1024 + s * 64 + kg * 16;
            __builtin_amdgcn_global_load_lds(
                (const __attribute__((address_space(1))) void*)src,
                (__attribute__((address_space(3))) void*)&xbl[f * 1024],
                16, 0, 0);
        }

        const float4 bv = *(const float4*)(bias + (size_t)e * CDIM + cBase
                                           + cs * 16 + kg * 4);

        __syncthreads();   // drains only x-frag loads (+bias) -- W not issued yet

        // ---- W: full-depth ring, all 16 loads issued NOW ----
        const float* wp = w + ((size_t)e * CDIM + cBase + cs * 16 + c16) * KDIM
                            + kh * 256 + kg * 8;
        float4 w0[8], w1[8];
        #pragma unroll
        for (int p = 0; p < 8; ++p) {
            w0[p] = LDF4(wp, p * 32);
            w1[p] = LDF4(wp, p * 32 + 4);
        }

        f32x4 acc0 = {0.f, 0.f, 0.f, 0.f};
        f32x4 acc1 = {0.f, 0.f, 0.f, 0.f};
        const char* xb = &xbl[(kh * 8) * 2048 + lane * 16];

        #pragma unroll
        for (int s = 0; s < 8; ++s) {
            const short8 a  = cvt8(w0[s], w1[s]);
            const short8 b0 = *(const short8*)(xb + s * 2048);
            const short8 b1 = *(const short8*)(xb + s * 2048 + 1024);
            acc0 = __builtin_amdgcn_mfma_f32_16x16x32_bf16(a, b0, acc0, 0, 0, 0);
            acc1 = __builtin_amdgcn_mfma_f32_16x16x32_bf16(a, b1, acc1, 0, 0, 0);
        }

        // ---- 2-way k-combine + lane-local GLU epilogue ----
        if (kh == 1) {
            #pragma unroll
            for (int i = 0; i < 4; ++i) {
                red[cs][lane][i]     = acc0[i];
                red[cs][lane][4 + i] = acc1[i];
            }
        }
        __syncthreads();
        if (kh == 0) {
            #pragma unroll
            for (int i = 0; i < 4; ++i) {
                acc0[i] += red[cs][lane][i];
                acc1[i] += red[cs][lane][4 + i];
            }
            const int cb = cBase + cs * 16 + kg * 4;   // channels cb..cb+3
            if (pr0 >= 0) {
                float2 o;
                o.x = glu_act(acc0[0] + bv.x, acc0[1] + bv.y);
                o.y = glu_act(acc0[2] + bv.z, acc0[3] + bv.w);
                *(float2*)&out[(size_t)pr0 * HALF_C + (cb >> 1)] = o;
            }
            if (pr1 >= 0) {
                float2 o;
                o.x = glu_act(acc1[0] + bv.x, acc1[1] + bv.y);
                o.y = glu_act(acc1[2] + bv.z, acc1[3] + bv.w);
                *(float2*)&out[(size_t)pr1 * HALF_C + (cb >> 1)] = o;
            }
        }
    }
}

extern "C" void kernel_launch(void* const* d_in, const int* in_sizes, int n_in,
                              void* d_out, int out_size, void* d_ws, size_t ws_size,
                              hipStream_t stream) {
    const float* x    = (const float*)d_in[0];
    const int*   idx  = (const int*)d_in[1];
    const float* w    = (const float*)d_in[2];
    const float* bias = (const float*)d_in[3];
    float* out = (float*)d_out;

    char* wsb = (char*)d_ws;
    unsigned short* lists = (unsigned short*)wsb;
    int* itemE  = (int*)(wsb + WS_ITEMS);
    int* itemB  = (int*)(wsb + WS_ITEMS + MAXIT * 4);
    int* itemN  = (int*)(wsb + WS_ITEMS + MAXIT * 8);
    int* nItems = (int*)(wsb + WS_ITEMS + MAXIT * 12);
    char* xpk   = wsb + WS_XPK;

    prep_kernel<<<33, 256, 0, stream>>>(x, (uint4*)xpk, idx, lists,
                                        itemE, itemB, itemN, nItems);

    dim3 grid(CDIM / 32, ITSTRIDE);   // (32, 32) = 1024 blocks = 4/CU
    moe_mlp1_kernel<<<grid, 256, 0, stream>>>(w, bias, xpk, lists,
                                              itemE, itemB, itemN, nItems, out);
}

// Round 9
// 20.675 us; speedup vs baseline: 1.6296x; 1.2152x over previous
//
#include <hip/hip_runtime.h>
#include <hip/hip_bf16.h>

// ---- problem constants ----
#define B_TOK   128
#define E_TOP   4
#define NEXP    32
#define KDIM    512
#define CDIM    1024
#define PAIRS   (B_TOK * E_TOP)   // 512
#define HALF_C  (CDIM / 2)        // 512

#define ALPHA   1.702f
#define LIMIT   7.0f

typedef __attribute__((ext_vector_type(8))) short short8;   // bf16x8 frag
typedef __attribute__((ext_vector_type(4))) float f32x4;

__device__ __forceinline__ unsigned pk2(float a, float b) {
    union { __hip_bfloat16 h; unsigned short u; } ca, cb;
    ca.h = __float2bfloat16(a);
    cb.h = __float2bfloat16(b);
    return (unsigned)ca.u | ((unsigned)cb.u << 16);
}

__device__ __forceinline__ short8 cvt8(float4 lo, float4 hi) {
    union { unsigned u[4]; short8 s; } r;
    r.u[0] = pk2(lo.x, lo.y);
    r.u[1] = pk2(lo.z, lo.w);
    r.u[2] = pk2(hi.x, hi.y);
    r.u[3] = pk2(hi.z, hi.w);
    return r.s;
}

__device__ __forceinline__ float glu_act(float g, float l) {
    g = fminf(g, LIMIT);
    l = fminf(fmaxf(l, -LIMIT), LIMIT);
    const float sg = 1.0f / (1.0f + __expf(-ALPHA * g));
    return (g * sg) * (l + 1.0f);
}

#define LDF4(p, off) (*(const float4*)((p) + (off)))

// =====================================================================
// Single fused kernel. Block = (32-ch chunk, expert); 4 waves =
// 2 k-halves x 2 ch-subgroups; wave tile = 16 ch x 32 tok x K/2.
//  1. inline bucket: scan idx[512] (L2-hot), collect this expert's
//     pairs via LDS atomicAdd (order-independent -> deterministic).
//  2. per 32-token chunk: stage x fp32 -> bf16 frag-linear LDS
//     (conflict-free ds_read_b128 in the K-loop).
//  3. K-loop: ALL 16 W dwordx4 issued after the stage barrier into a
//     VGPR ring; 16 MFMAs/wave; no barrier touches the W stream.
//  4. 2-way k-combine via 4 KB LDS; lane-local interleaved-GLU epilogue.
// No workspace, no second kernel, no inter-kernel dependency.
// =====================================================================
__global__ __launch_bounds__(256, 4) void moe_mlp1_kernel(
    const float* __restrict__ x,      // [128, 512]
    const int* __restrict__ idx,      // [128, 4]
    const float* __restrict__ w,      // [32, 1024, 512]
    const float* __restrict__ bias,   // [32, 1024]
    float* __restrict__ out)          // [512, 512] fp32
{
    __shared__ char  xbl[32 * 1024];       // 32 frags x 1 KB
    __shared__ float red[2][64][8];        // 4 KB k-combine
    __shared__ unsigned short list[PAIRS]; // 1 KB
    __shared__ int cnt;

    const int e     = blockIdx.y;
    const int cBase = blockIdx.x * 32;
    const int tid   = threadIdx.x;
    const int wv    = tid >> 6;
    const int lane  = tid & 63;
    const int kh    = wv >> 1;         // k-half
    const int cs    = wv & 1;          // channel sub-group
    const int kg    = lane >> 4;       // k-group within MFMA step
    const int c16   = lane & 15;
    const int tA    = lane & 15;

    // ---- 1. inline bucket ----
    if (tid == 0) cnt = 0;
    __syncthreads();
    #pragma unroll
    for (int r = 0; r < 2; ++r) {
        const int p = tid + r * 256;
        if (idx[p] == e) {
            const int pos = atomicAdd(&cnt, 1);
            list[pos] = (unsigned short)p;
        }
    }
    __syncthreads();
    const int T = cnt;

    // hoisted per-block constants
    const float* wp = w + ((size_t)e * CDIM + cBase + cs * 16 + c16) * KDIM
                        + kh * 256 + kg * 8;
    const float4 bv = *(const float4*)(bias + (size_t)e * CDIM + cBase
                                       + cs * 16 + kg * 4);
    const int cb = cBase + cs * 16 + kg * 4;   // epilogue channels cb..cb+3

    for (int tb = 0; tb < T; tb += 32) {
        if (tb) __syncthreads();               // xbl/red reuse guard
        const int nT = min(32, T - tb);

        // ---- 2. stage x chunk: fp32 -> bf16, frag-linear LDS ----
        // unit u: token t = u&31, step s = u>>5 (32 k's). Frag f = s*2 +
        // (t>>4); lane l = t16 + 16*kg holds (tok t16, k = kg*8..+8).
        #pragma unroll
        for (int r = 0; r < 2; ++r) {
            const int u = tid + r * 256;
            const int t = u & 31;
            const int s = u >> 5;
            const int pr = (int)list[tb + ((t < nT) ? t : 0)];
            const float* xr = x + (size_t)(pr >> 2) * KDIM + s * 32;
            const float4 f0 = LDF4(xr, 0),  f1 = LDF4(xr, 4);
            const float4 f2 = LDF4(xr, 8),  f3 = LDF4(xr, 12);
            const float4 f4 = LDF4(xr, 16), f5 = LDF4(xr, 20);
            const float4 f6 = LDF4(xr, 24), f7 = LDF4(xr, 28);
            char* db = &xbl[(s * 2 + (t >> 4)) * 1024 + (t & 15) * 16];
            *(short8*)(db + 0 * 256) = cvt8(f0, f1);
            *(short8*)(db + 1 * 256) = cvt8(f2, f3);
            *(short8*)(db + 2 * 256) = cvt8(f4, f5);
            *(short8*)(db + 3 * 256) = cvt8(f6, f7);
        }

        // output token rows
        const int pr0 = (tA < nT)      ? (int)list[tb + tA]      : -1;
        const int pr1 = (tA + 16 < nT) ? (int)list[tb + tA + 16] : -1;

        __syncthreads();   // frags ready; drains only x loads (W not issued)

        // ---- 3. W: full stream into VGPR ring, then 16 MFMAs ----
        float4 w0[8], w1[8];
        #pragma unroll
        for (int p = 0; p < 8; ++p) {
            w0[p] = LDF4(wp, p * 32);
            w1[p] = LDF4(wp, p * 32 + 4);
        }

        f32x4 acc0 = {0.f, 0.f, 0.f, 0.f};
        f32x4 acc1 = {0.f, 0.f, 0.f, 0.f};
        const char* xb = &xbl[(kh * 8) * 2048 + lane * 16];

        #pragma unroll
        for (int s = 0; s < 8; ++s) {
            const short8 a  = cvt8(w0[s], w1[s]);
            const short8 b0 = *(const short8*)(xb + s * 2048);
            const short8 b1 = *(const short8*)(xb + s * 2048 + 1024);
            acc0 = __builtin_amdgcn_mfma_f32_16x16x32_bf16(a, b0, acc0, 0, 0, 0);
            acc1 = __builtin_amdgcn_mfma_f32_16x16x32_bf16(a, b1, acc1, 0, 0, 0);
        }

        // ---- 4. 2-way k-combine + lane-local GLU epilogue ----
        if (kh == 1) {
            #pragma unroll
            for (int i = 0; i < 4; ++i) {
                red[cs][lane][i]     = acc0[i];
                red[cs][lane][4 + i] = acc1[i];
            }
        }
        __syncthreads();
        if (kh == 0) {
            #pragma unroll
            for (int i = 0; i < 4; ++i) {
                acc0[i] += red[cs][lane][i];
                acc1[i] += red[cs][lane][4 + i];
            }
            if (pr0 >= 0) {
                float2 o;
                o.x = glu_act(acc0[0] + bv.x, acc0[1] + bv.y);
                o.y = glu_act(acc0[2] + bv.z, acc0[3] + bv.w);
                *(float2*)&out[(size_t)pr0 * HALF_C + (cb >> 1)] = o;
            }
            if (pr1 >= 0) {
                float2 o;
                o.x = glu_act(acc1[0] + bv.x, acc1[1] + bv.y);
                o.y = glu_act(acc1[2] + bv.z, acc1[3] + bv.w);
                *(float2*)&out[(size_t)pr1 * HALF_C + (cb >> 1)] = o;
            }
        }
    }
}

extern "C" void kernel_launch(void* const* d_in, const int* in_sizes, int n_in,
                              void* d_out, int out_size, void* d_ws, size_t ws_size,
                              hipStream_t stream) {
    const float* x    = (const float*)d_in[0];
    const int*   idx  = (const int*)d_in[1];
    const float* w    = (const float*)d_in[2];
    const float* bias = (const float*)d_in[3];
    float* out = (float*)d_out;

    dim3 grid(CDIM / 32, NEXP);   // (32, 32) = 1024 blocks = 4/CU
    moe_mlp1_kernel<<<grid, 256, 0, stream>>>(x, idx, w, bias, out);
}